// Round 1
// 219.765 us; speedup vs baseline: 1.0866x; 1.0866x over previous
//
#include <hip/hip_runtime.h>
#include <hip/hip_bf16.h>

// RoutingLayer: B=128,S=64,N=32, D=128, K=8 capsules x C=16, 3 routing iters.
// fp32 inputs, split-bf16 MFMA GEMM (hi*hi + hi*lo + lo*hi), fused routing.
// R6 (occupancy + latency-hiding pass):
//  - uu folded into dead Alo tail -> LDS 20704->20192 B -> 8 blocks/CU (was 7)
//  - __launch_bounds__(256,8): VGPR cap 64 (compiler previously chose 48)
//  - kt=0 W-frag loads + bias loads hoisted above the staging barrier;
//    1-deep W-frag prefetch rotation through the kt loop (hide ~200cyc L2 hits
//    under the 18 MFMAs of the previous kt)
//  - staging split packs via v_perm_b32: 12 VALU / float4 instead of 24,
//    bit-identical truncation split
//  - detect folded into swizzle kernel (one fewer launch)

#define NB 32
#define DD 128
#define ZS 132   // zn row stride (floats)
#define PPS 37   // pp row stride (floats) — kills diagonal write conflicts
#define AST 136  // staged A row stride (bf16 units) = 272 B, 16B-aligned

// LDS layout (bytes):
// [0, 8976)      Ahi 33x136 bf16   } union with: zn fp32 33x132 = [0,17408)
// [8976, 17952)  Alo 33x136 bf16   }            uu 128 f32      = [17408,17920)
// [17952, 19008) nrm 264 f32
// [19008, 20192) pp  8x37 f32
#define SMEM_BYTES 20192
#define ALO_OFF_SH 4488
#define UU_OFF_F 4352
#define NRM_OFF_F 4488
#define PP_OFF_F 4752

typedef __attribute__((ext_vector_type(8))) short bf16x8;
typedef __attribute__((ext_vector_type(4))) float f32x4;
typedef __attribute__((ext_vector_type(4))) float float4v;
typedef __attribute__((ext_vector_type(2))) unsigned int uint2v;

__device__ __forceinline__ float bf16bits_to_f32(unsigned short u) {
  return __uint_as_float(((unsigned int)u) << 16);
}
__device__ __forceinline__ void split_bf16(float x, unsigned short& hi, unsigned short& lo) {
  unsigned int xb = __float_as_uint(x);
  hi = (unsigned short)(xb >> 16);
  float hif = __uint_as_float(xb & 0xFFFF0000u);
  float lof = x - hif;  // exact
  lo = (unsigned short)(__float_as_uint(lof) >> 16);
}

// Truncation split of 4 floats into packed hi/lo bf16 pairs via v_perm_b32.
// Bit-identical to split_bf16 + shift/or packing, at half the VALU ops.
__device__ __forceinline__ void split4_store(float4v v, unsigned short* hp,
                                             unsigned short* lp) {
  unsigned int a = __float_as_uint(v[0]);
  unsigned int b = __float_as_uint(v[1]);
  unsigned int c = __float_as_uint(v[2]);
  unsigned int d = __float_as_uint(v[3]);
  // D = {S1.b2, S1.b3, S0.b2, S0.b3} -> low short = hi16(first), high = hi16(second)
  unsigned int h01 = __builtin_amdgcn_perm(b, a, 0x07060302u);
  unsigned int h23 = __builtin_amdgcn_perm(d, c, 0x07060302u);
  unsigned int la = __float_as_uint(v[0] - __uint_as_float(a & 0xFFFF0000u));
  unsigned int lb = __float_as_uint(v[1] - __uint_as_float(b & 0xFFFF0000u));
  unsigned int lc = __float_as_uint(v[2] - __uint_as_float(c & 0xFFFF0000u));
  unsigned int ld = __float_as_uint(v[3] - __uint_as_float(d & 0xFFFF0000u));
  unsigned int l01 = __builtin_amdgcn_perm(lb, la, 0x07060302u);
  unsigned int l23 = __builtin_amdgcn_perm(ld, lc, 0x07060302u);
  *(uint2v*)hp = (uint2v){h01, h23};
  *(uint2v*)lp = (uint2v){l01, l23};
}

// W (k-major 128x128) -> MFMA-B fragment-major hi/lo bf16. Self-detects dtype
// (ballot on wave 0); block 0 publishes flag for routing_kernel.
__global__ __launch_bounds__(256) void swizzle_w_kernel(
    const void* __restrict__ w1, int* __restrict__ flag,
    unsigned short* __restrict__ whi, unsigned short* __restrict__ wlo) {
  __shared__ int sflag;
  int t = threadIdx.x;
  if (t < 64) {
    float v = bf16bits_to_f32(((const unsigned short*)w1)[2 * t]);
    int hit = !(fabsf(v) < 1e4f);
    unsigned long long m = __ballot(hit);
    if (t == 0) sflag = (m != 0ull) ? 1 : 0;
  }
  __syncthreads();
  const int isf = sflag;
  if (blockIdx.x == 0 && t == 0) *flag = isf;

  int idx = blockIdx.x * 256 + t;
  int k = idx >> 7, n = idx & 127;
  int kt = k >> 5, q = (k >> 3) & 3, j = k & 7;
  int nt = n >> 4, nl = n & 15;
  int lane = q * 16 + nl;
  int dst = ((kt * 8 + nt) * 64 + lane) * 8 + j;
  unsigned short hb, lb;
  if (isf) {
    split_bf16(((const float*)w1)[idx], hb, lb);
  } else {
    hb = ((const unsigned short*)w1)[idx];
    lb = 0;
  }
  whi[dst] = hb;
  wlo[dst] = lb;
}

__global__ __launch_bounds__(256, 8) void routing_kernel(
    const void* __restrict__ selfv,
    const void* __restrict__ neighv,
    const unsigned short* __restrict__ whi,
    const unsigned short* __restrict__ wlo,
    const void* __restrict__ b1,
    void* __restrict__ out,
    const int* __restrict__ flag) {
  __shared__ __align__(16) unsigned char smem[SMEM_BYTES];
  unsigned short* Ahi = (unsigned short*)smem;
  unsigned short* Alo = Ahi + ALO_OFF_SH;
  float* zn = (float*)smem;  // union: valid after GEMM
  float* uu = (float*)smem + UU_OFF_F;   // union with Alo tail: valid after GEMM
  float* nrm = (float*)smem + NRM_OFF_F;
  float* pp = (float*)smem + PP_OFF_F;

  const int tid = threadIdx.x;
  const int lane = tid & 63;
  const int wv = tid >> 6;
  const int q = lane >> 4;
  const int ml = lane & 15;
  const size_t bs = blockIdx.x;
  const bool isf32 = (*flag != 0);

  const size_t noff = bs * (size_t)(NB * DD);
  const size_t soff = bs * (size_t)DD;

  // ---------------- Stage A (33x128) into LDS as hi/lo bf16, convert ONCE ----
  if (isf32) {
    const float* nf = (const float*)neighv + noff;
    const float* sf = (const float*)selfv + soff;
#pragma unroll
    for (int i = 0; i < 4; ++i) {
      int f = tid + (i << 8);  // float4 index 0..1023
      int r = f >> 5, c4 = f & 31;
      float4v v = ((const float4v*)nf)[f];
      split4_store(v, Ahi + r * AST + c4 * 4, Alo + r * AST + c4 * 4);
    }
    if (tid < 32) {
      float4v v = ((const float4v*)sf)[tid];
      split4_store(v, Ahi + 32 * AST + tid * 4, Alo + 32 * AST + tid * 4);
    }
  } else {
    const unsigned short* nbf = (const unsigned short*)neighv + noff;
    const unsigned short* sbf = (const unsigned short*)selfv + soff;
    const bf16x8 zv = (bf16x8){0, 0, 0, 0, 0, 0, 0, 0};
#pragma unroll
    for (int i = 0; i < 2; ++i) {
      int s = tid + (i << 8);  // 16B chunk 0..511
      int r = s >> 4, c8 = s & 15;
      bf16x8 v = *(const bf16x8*)(nbf + r * DD + c8 * 8);
      *(bf16x8*)(Ahi + r * AST + c8 * 8) = v;
      *(bf16x8*)(Alo + r * AST + c8 * 8) = zv;
    }
    if (tid < 16) {
      bf16x8 v = *(const bf16x8*)(sbf + tid * 8);
      *(bf16x8*)(Ahi + 32 * AST + tid * 8) = v;
      *(bf16x8*)(Alo + 32 * AST + tid * 8) = zv;
    }
  }

  // Hoisted above the barrier: kt=0 W fragments + bias (independent of LDS;
  // their L2 latency is absorbed by the barrier wait).
  const int nt0 = wv, nt1 = wv + 4;
  size_t bo0 = ((size_t)(0 * 8 + nt0) * 64 + lane) * 8;
  size_t bo1 = ((size_t)(0 * 8 + nt1) * 64 + lane) * 8;
  bf16x8 nb0h = *(const bf16x8*)(whi + bo0);
  bf16x8 nb0l = *(const bf16x8*)(wlo + bo0);
  bf16x8 nb1h = *(const bf16x8*)(whi + bo1);
  bf16x8 nb1l = *(const bf16x8*)(wlo + bo1);
  float bias0, bias1;
  if (isf32) {
    bias0 = ((const float*)b1)[nt0 * 16 + ml];
    bias1 = ((const float*)b1)[nt1 * 16 + ml];
  } else {
    bias0 = bf16bits_to_f32(((const unsigned short*)b1)[nt0 * 16 + ml]);
    bias1 = bf16bits_to_f32(((const unsigned short*)b1)[nt1 * 16 + ml]);
  }
  __syncthreads();

  // ---------------- GEMM: Z[48x128] = X @ W, split-bf16, frags from LDS ------
  f32x4 acc[3][2];
#pragma unroll
  for (int mt = 0; mt < 3; ++mt)
#pragma unroll
    for (int jn = 0; jn < 2; ++jn) acc[mt][jn] = (f32x4){0.f, 0.f, 0.f, 0.f};

#pragma unroll
  for (int kt = 0; kt < 4; ++kt) {
    bf16x8 b0h = nb0h, b0l = nb0l, b1h = nb1h, b1l = nb1l;
    if (kt < 3) {  // prefetch next kt's W frags under this kt's MFMAs
      const size_t pbo0 = ((size_t)((kt + 1) * 8 + nt0) * 64 + lane) * 8;
      const size_t pbo1 = ((size_t)((kt + 1) * 8 + nt1) * 64 + lane) * 8;
      nb0h = *(const bf16x8*)(whi + pbo0);
      nb0l = *(const bf16x8*)(wlo + pbo0);
      nb1h = *(const bf16x8*)(whi + pbo1);
      nb1l = *(const bf16x8*)(wlo + pbo1);
    }
    const int fo = kt * 32 + q * 8;
    bf16x8 a0h = *(const bf16x8*)(Ahi + ml * AST + fo);
    bf16x8 a0l = *(const bf16x8*)(Alo + ml * AST + fo);
    bf16x8 a1h = *(const bf16x8*)(Ahi + (16 + ml) * AST + fo);
    bf16x8 a1l = *(const bf16x8*)(Alo + (16 + ml) * AST + fo);
    bf16x8 a2h = *(const bf16x8*)(Ahi + 32 * AST + fo);  // broadcast row
    bf16x8 a2l = *(const bf16x8*)(Alo + 32 * AST + fo);

    acc[0][0] = __builtin_amdgcn_mfma_f32_16x16x32_bf16(a0h, b0h, acc[0][0], 0, 0, 0);
    acc[0][1] = __builtin_amdgcn_mfma_f32_16x16x32_bf16(a0h, b1h, acc[0][1], 0, 0, 0);
    acc[1][0] = __builtin_amdgcn_mfma_f32_16x16x32_bf16(a1h, b0h, acc[1][0], 0, 0, 0);
    acc[1][1] = __builtin_amdgcn_mfma_f32_16x16x32_bf16(a1h, b1h, acc[1][1], 0, 0, 0);
    acc[2][0] = __builtin_amdgcn_mfma_f32_16x16x32_bf16(a2h, b0h, acc[2][0], 0, 0, 0);
    acc[2][1] = __builtin_amdgcn_mfma_f32_16x16x32_bf16(a2h, b1h, acc[2][1], 0, 0, 0);
    acc[0][0] = __builtin_amdgcn_mfma_f32_16x16x32_bf16(a0h, b0l, acc[0][0], 0, 0, 0);
    acc[0][1] = __builtin_amdgcn_mfma_f32_16x16x32_bf16(a0h, b1l, acc[0][1], 0, 0, 0);
    acc[1][0] = __builtin_amdgcn_mfma_f32_16x16x32_bf16(a1h, b0l, acc[1][0], 0, 0, 0);
    acc[1][1] = __builtin_amdgcn_mfma_f32_16x16x32_bf16(a1h, b1l, acc[1][1], 0, 0, 0);
    acc[2][0] = __builtin_amdgcn_mfma_f32_16x16x32_bf16(a2h, b0l, acc[2][0], 0, 0, 0);
    acc[2][1] = __builtin_amdgcn_mfma_f32_16x16x32_bf16(a2h, b1l, acc[2][1], 0, 0, 0);
    acc[0][0] = __builtin_amdgcn_mfma_f32_16x16x32_bf16(a0l, b0h, acc[0][0], 0, 0, 0);
    acc[0][1] = __builtin_amdgcn_mfma_f32_16x16x32_bf16(a0l, b1h, acc[0][1], 0, 0, 0);
    acc[1][0] = __builtin_amdgcn_mfma_f32_16x16x32_bf16(a1l, b0h, acc[1][0], 0, 0, 0);
    acc[1][1] = __builtin_amdgcn_mfma_f32_16x16x32_bf16(a1l, b1h, acc[1][1], 0, 0, 0);
    acc[2][0] = __builtin_amdgcn_mfma_f32_16x16x32_bf16(a2l, b0h, acc[2][0], 0, 0, 0);
    acc[2][1] = __builtin_amdgcn_mfma_f32_16x16x32_bf16(a2l, b1h, acc[2][1], 0, 0, 0);
  }
  __syncthreads();  // all waves done reading Ahi/Alo before zn/uu overwrite them

  // Epilogue: bias + relu -> RAW zn (fp32) over the staging region.
#pragma unroll
  for (int jn = 0; jn < 2; ++jn) {
    const int nt = jn ? nt1 : nt0;
    const int col = nt * 16 + ml;
    const float bias = jn ? bias1 : bias0;
#pragma unroll
    for (int mt = 0; mt < 3; ++mt) {
#pragma unroll
      for (int r = 0; r < 4; ++r) {
        const int row = mt * 16 + q * 4 + r;
        float v = fmaxf(acc[mt][jn][r] + bias, 0.f);
        if (row < 33) zn[row * ZS + col] = v;
      }
    }
  }
  __syncthreads();

  // Norms per (row,k); seed pp for iter 0 (uniform p=1/8, nrm folded).
  for (int id = tid; id < 264; id += 256) {
    const int row = id >> 3, k = id & 7;
    const float4v* zp = (const float4v*)&zn[row * ZS + k * 16];
    float4v a = zp[0], b = zp[1], c = zp[2], d = zp[3];
    float ss = a[0]*a[0]+a[1]*a[1]+a[2]*a[2]+a[3]*a[3]
             + b[0]*b[0]+b[1]*b[1]+b[2]*b[2]+b[3]*b[3]
             + c[0]*c[0]+c[1]*c[1]+c[2]*c[2]+c[3]*c[3]
             + d[0]*d[0]+d[1]*d[1]+d[2]*d[2]+d[3]*d[3];
    float nv = 1.f / fmaxf(sqrtf(ss), 1e-12f);
    nrm[id] = nv;
    if (row < 32) pp[k * PPS + row] = nv * 0.125f;
  }
  __syncthreads();

  // ---------------- Routing: 3 iterations ----------------
  const int k2 = tid >> 5, half = (tid >> 4) & 1, c2 = tid & 15;
  for (int it = 0; it < 3; ++it) {
    if (it > 0) {
      // pass1: logits per (n,k); softmax over k; pp[k][n] = prob * nrm[n,k].
      const int n1 = tid >> 3, k1 = tid & 7;
      const float4v* up = (const float4v*)&uu[k1 * 16];
      float4v u0 = up[0], u1 = up[1], u2 = up[2], u3 = up[3];
      const float4v* zp = (const float4v*)&zn[n1 * ZS + k1 * 16];
      float4v z0 = zp[0], z1 = zp[1], z2 = zp[2], z3 = zp[3];
      float dot = u0[0]*z0[0]+u0[1]*z0[1]+u0[2]*z0[2]+u0[3]*z0[3]
                + u1[0]*z1[0]+u1[1]*z1[1]+u1[2]*z1[2]+u1[3]*z1[3]
                + u2[0]*z2[0]+u2[1]*z2[1]+u2[2]*z2[2]+u2[3]*z2[3]
                + u3[0]*z3[0]+u3[1]*z3[1]+u3[2]*z3[2]+u3[3]*z3[3];
      const float nv = nrm[n1 * 8 + k1];
      float logit = dot * nv;  // TAU = 1
      float m = logit;
      m = fmaxf(m, __shfl_xor(m, 1));
      m = fmaxf(m, __shfl_xor(m, 2));
      m = fmaxf(m, __shfl_xor(m, 4));
      float e = __expf(logit - m);
      float s = e;
      s += __shfl_xor(s, 1);
      s += __shfl_xor(s, 2);
      s += __shfl_xor(s, 4);
      pp[k1 * PPS + n1] = (e / s) * nv;
      __syncthreads();
    }
    // pass2: 256 threads; (k2,c2) duplicated over half; each half sums 16 n's.
    float s = 0.f;
#pragma unroll
    for (int n0 = 0; n0 < 16; ++n0) {
      const int n = half * 16 + n0;
      s += pp[k2 * PPS + n] * zn[n * ZS + k2 * 16 + c2];
    }
    s += __shfl_xor(s, 16);                       // combine halves
    s += nrm[256 + k2] * zn[32 * ZS + k2 * 16 + c2];  // self capsule
    if (it < 2) {
      float ss = s * s;
      ss += __shfl_xor(ss, 1);
      ss += __shfl_xor(ss, 2);
      ss += __shfl_xor(ss, 4);
      ss += __shfl_xor(ss, 8);
      s *= 1.f / fmaxf(sqrtf(ss), 1e-12f);
      if (half == 0) uu[k2 * 16 + c2] = s;
    } else if (half == 0) {
      float r = (s < 0.f) ? 0.f : s;
      const size_t oidx = bs * DD + k2 * 16 + c2;
      if (isf32) {
        ((float*)out)[oidx] = r;
      } else {
        unsigned int xb = __float_as_uint(r);
        unsigned int l = (xb >> 16) & 1u;
        ((unsigned short*)out)[oidx] = (unsigned short)((xb + 0x7fffu + l) >> 16);
      }
    }
    __syncthreads();
  }
}

extern "C" void kernel_launch(void* const* d_in, const int* in_sizes, int n_in,
                              void* d_out, int out_size, void* d_ws, size_t ws_size,
                              hipStream_t stream) {
  (void)in_sizes; (void)n_in; (void)out_size; (void)ws_size;
  const void* selfv = d_in[0];
  const void* neighv = d_in[1];
  const void* w1 = d_in[2];
  const void* b1 = d_in[3];
  int* flag = (int*)d_ws;
  unsigned short* whi = (unsigned short*)((char*)d_ws + 64);
  unsigned short* wlo = (unsigned short*)((char*)d_ws + 64 + 32768);

  swizzle_w_kernel<<<64, 256, 0, stream>>>(w1, flag, whi, wlo);
  routing_kernel<<<8192, 256, 0, stream>>>(selfv, neighv, whi, wlo, b1, d_out, flag);
}

// Round 2
// 218.619 us; speedup vs baseline: 1.0922x; 1.0052x over previous
//
#include <hip/hip_runtime.h>
#include <hip/hip_bf16.h>

// RoutingLayer: B=128,S=64,N=32, D=128, K=8 capsules x C=16, 3 routing iters.
// fp32 inputs, split-bf16 MFMA GEMM (hi*hi + hi*lo + lo*hi), fused routing.
// R7 (LDS bank-conflict pass):
//  - norms/pass1 lane remap: row fast-varying, k slow ((l>>3)&7) -> consecutive
//    lanes hit distinct 528B-strided rows -> kills the 4-way b128 conflicts
//    (softmax shfl masks become 8,16,32)
//  - PPS 37->40: pp rows 16B-aligned -> pass2 reads p as 4 broadcast float4
//    instead of 16 scalar ds_read_b32
//  - self-capsule zn/nrm loads hoisted out of the routing loop (invariant)
//  - dead final-iteration barrier removed

#define NB 32
#define DD 128
#define ZS 132   // zn row stride (floats)
#define PPS 40   // pp row stride (floats) — 160B, 16B-aligned, conflict-free writes
#define AST 136  // staged A row stride (bf16 units) = 272 B, 16B-aligned

// LDS layout (bytes):
// [0, 8976)      Ahi 33x136 bf16   } union with: zn fp32 33x132 = [0,17408)
// [8976, 17952)  Alo 33x136 bf16   }            uu 128 f32      = [17408,17920)
// [17952, 19008) nrm 264 f32
// [19008, 20288) pp  8x40 f32
#define SMEM_BYTES 20288
#define ALO_OFF_SH 4488
#define UU_OFF_F 4352
#define NRM_OFF_F 4488
#define PP_OFF_F 4752

typedef __attribute__((ext_vector_type(8))) short bf16x8;
typedef __attribute__((ext_vector_type(4))) float f32x4;
typedef __attribute__((ext_vector_type(4))) float float4v;
typedef __attribute__((ext_vector_type(2))) unsigned int uint2v;

__device__ __forceinline__ float bf16bits_to_f32(unsigned short u) {
  return __uint_as_float(((unsigned int)u) << 16);
}
__device__ __forceinline__ void split_bf16(float x, unsigned short& hi, unsigned short& lo) {
  unsigned int xb = __float_as_uint(x);
  hi = (unsigned short)(xb >> 16);
  float hif = __uint_as_float(xb & 0xFFFF0000u);
  float lof = x - hif;  // exact
  lo = (unsigned short)(__float_as_uint(lof) >> 16);
}

// Truncation split of 4 floats into packed hi/lo bf16 pairs via v_perm_b32.
// Bit-identical to split_bf16 + shift/or packing, at half the VALU ops.
__device__ __forceinline__ void split4_store(float4v v, unsigned short* hp,
                                             unsigned short* lp) {
  unsigned int a = __float_as_uint(v[0]);
  unsigned int b = __float_as_uint(v[1]);
  unsigned int c = __float_as_uint(v[2]);
  unsigned int d = __float_as_uint(v[3]);
  // D = {S1.b2, S1.b3, S0.b2, S0.b3} -> low short = hi16(first), high = hi16(second)
  unsigned int h01 = __builtin_amdgcn_perm(b, a, 0x07060302u);
  unsigned int h23 = __builtin_amdgcn_perm(d, c, 0x07060302u);
  unsigned int la = __float_as_uint(v[0] - __uint_as_float(a & 0xFFFF0000u));
  unsigned int lb = __float_as_uint(v[1] - __uint_as_float(b & 0xFFFF0000u));
  unsigned int lc = __float_as_uint(v[2] - __uint_as_float(c & 0xFFFF0000u));
  unsigned int ld = __float_as_uint(v[3] - __uint_as_float(d & 0xFFFF0000u));
  unsigned int l01 = __builtin_amdgcn_perm(lb, la, 0x07060302u);
  unsigned int l23 = __builtin_amdgcn_perm(ld, lc, 0x07060302u);
  *(uint2v*)hp = (uint2v){h01, h23};
  *(uint2v*)lp = (uint2v){l01, l23};
}

// W (k-major 128x128) -> MFMA-B fragment-major hi/lo bf16. Self-detects dtype
// (ballot on wave 0); block 0 publishes flag for routing_kernel.
__global__ __launch_bounds__(256) void swizzle_w_kernel(
    const void* __restrict__ w1, int* __restrict__ flag,
    unsigned short* __restrict__ whi, unsigned short* __restrict__ wlo) {
  __shared__ int sflag;
  int t = threadIdx.x;
  if (t < 64) {
    float v = bf16bits_to_f32(((const unsigned short*)w1)[2 * t]);
    int hit = !(fabsf(v) < 1e4f);
    unsigned long long m = __ballot(hit);
    if (t == 0) sflag = (m != 0ull) ? 1 : 0;
  }
  __syncthreads();
  const int isf = sflag;
  if (blockIdx.x == 0 && t == 0) *flag = isf;

  int idx = blockIdx.x * 256 + t;
  int k = idx >> 7, n = idx & 127;
  int kt = k >> 5, q = (k >> 3) & 3, j = k & 7;
  int nt = n >> 4, nl = n & 15;
  int lane = q * 16 + nl;
  int dst = ((kt * 8 + nt) * 64 + lane) * 8 + j;
  unsigned short hb, lb;
  if (isf) {
    split_bf16(((const float*)w1)[idx], hb, lb);
  } else {
    hb = ((const unsigned short*)w1)[idx];
    lb = 0;
  }
  whi[dst] = hb;
  wlo[dst] = lb;
}

__global__ __launch_bounds__(256, 8) void routing_kernel(
    const void* __restrict__ selfv,
    const void* __restrict__ neighv,
    const unsigned short* __restrict__ whi,
    const unsigned short* __restrict__ wlo,
    const void* __restrict__ b1,
    void* __restrict__ out,
    const int* __restrict__ flag) {
  __shared__ __align__(16) unsigned char smem[SMEM_BYTES];
  unsigned short* Ahi = (unsigned short*)smem;
  unsigned short* Alo = Ahi + ALO_OFF_SH;
  float* zn = (float*)smem;  // union: valid after GEMM
  float* uu = (float*)smem + UU_OFF_F;   // union with Alo tail: valid after GEMM
  float* nrm = (float*)smem + NRM_OFF_F;
  float* pp = (float*)smem + PP_OFF_F;

  const int tid = threadIdx.x;
  const int lane = tid & 63;
  const int wv = tid >> 6;
  const int q = lane >> 4;
  const int ml = lane & 15;
  const size_t bs = blockIdx.x;
  const bool isf32 = (*flag != 0);

  const size_t noff = bs * (size_t)(NB * DD);
  const size_t soff = bs * (size_t)DD;

  // ---------------- Stage A (33x128) into LDS as hi/lo bf16, convert ONCE ----
  if (isf32) {
    const float* nf = (const float*)neighv + noff;
    const float* sf = (const float*)selfv + soff;
#pragma unroll
    for (int i = 0; i < 4; ++i) {
      int f = tid + (i << 8);  // float4 index 0..1023
      int r = f >> 5, c4 = f & 31;
      float4v v = ((const float4v*)nf)[f];
      split4_store(v, Ahi + r * AST + c4 * 4, Alo + r * AST + c4 * 4);
    }
    if (tid < 32) {
      float4v v = ((const float4v*)sf)[tid];
      split4_store(v, Ahi + 32 * AST + tid * 4, Alo + 32 * AST + tid * 4);
    }
  } else {
    const unsigned short* nbf = (const unsigned short*)neighv + noff;
    const unsigned short* sbf = (const unsigned short*)selfv + soff;
    const bf16x8 zv = (bf16x8){0, 0, 0, 0, 0, 0, 0, 0};
#pragma unroll
    for (int i = 0; i < 2; ++i) {
      int s = tid + (i << 8);  // 16B chunk 0..511
      int r = s >> 4, c8 = s & 15;
      bf16x8 v = *(const bf16x8*)(nbf + r * DD + c8 * 8);
      *(bf16x8*)(Ahi + r * AST + c8 * 8) = v;
      *(bf16x8*)(Alo + r * AST + c8 * 8) = zv;
    }
    if (tid < 16) {
      bf16x8 v = *(const bf16x8*)(sbf + tid * 8);
      *(bf16x8*)(Ahi + 32 * AST + tid * 8) = v;
      *(bf16x8*)(Alo + 32 * AST + tid * 8) = zv;
    }
  }

  // Hoisted above the barrier: kt=0 W fragments + bias (independent of LDS;
  // their L2 latency is absorbed by the barrier wait).
  const int nt0 = wv, nt1 = wv + 4;
  size_t bo0 = ((size_t)(0 * 8 + nt0) * 64 + lane) * 8;
  size_t bo1 = ((size_t)(0 * 8 + nt1) * 64 + lane) * 8;
  bf16x8 nb0h = *(const bf16x8*)(whi + bo0);
  bf16x8 nb0l = *(const bf16x8*)(wlo + bo0);
  bf16x8 nb1h = *(const bf16x8*)(whi + bo1);
  bf16x8 nb1l = *(const bf16x8*)(wlo + bo1);
  float bias0, bias1;
  if (isf32) {
    bias0 = ((const float*)b1)[nt0 * 16 + ml];
    bias1 = ((const float*)b1)[nt1 * 16 + ml];
  } else {
    bias0 = bf16bits_to_f32(((const unsigned short*)b1)[nt0 * 16 + ml]);
    bias1 = bf16bits_to_f32(((const unsigned short*)b1)[nt1 * 16 + ml]);
  }
  __syncthreads();

  // ---------------- GEMM: Z[48x128] = X @ W, split-bf16, frags from LDS ------
  f32x4 acc[3][2];
#pragma unroll
  for (int mt = 0; mt < 3; ++mt)
#pragma unroll
    for (int jn = 0; jn < 2; ++jn) acc[mt][jn] = (f32x4){0.f, 0.f, 0.f, 0.f};

#pragma unroll
  for (int kt = 0; kt < 4; ++kt) {
    bf16x8 b0h = nb0h, b0l = nb0l, b1h = nb1h, b1l = nb1l;
    if (kt < 3) {  // prefetch next kt's W frags under this kt's MFMAs
      const size_t pbo0 = ((size_t)((kt + 1) * 8 + nt0) * 64 + lane) * 8;
      const size_t pbo1 = ((size_t)((kt + 1) * 8 + nt1) * 64 + lane) * 8;
      nb0h = *(const bf16x8*)(whi + pbo0);
      nb0l = *(const bf16x8*)(wlo + pbo0);
      nb1h = *(const bf16x8*)(whi + pbo1);
      nb1l = *(const bf16x8*)(wlo + pbo1);
    }
    const int fo = kt * 32 + q * 8;
    bf16x8 a0h = *(const bf16x8*)(Ahi + ml * AST + fo);
    bf16x8 a0l = *(const bf16x8*)(Alo + ml * AST + fo);
    bf16x8 a1h = *(const bf16x8*)(Ahi + (16 + ml) * AST + fo);
    bf16x8 a1l = *(const bf16x8*)(Alo + (16 + ml) * AST + fo);
    bf16x8 a2h = *(const bf16x8*)(Ahi + 32 * AST + fo);  // broadcast row
    bf16x8 a2l = *(const bf16x8*)(Alo + 32 * AST + fo);

    acc[0][0] = __builtin_amdgcn_mfma_f32_16x16x32_bf16(a0h, b0h, acc[0][0], 0, 0, 0);
    acc[0][1] = __builtin_amdgcn_mfma_f32_16x16x32_bf16(a0h, b1h, acc[0][1], 0, 0, 0);
    acc[1][0] = __builtin_amdgcn_mfma_f32_16x16x32_bf16(a1h, b0h, acc[1][0], 0, 0, 0);
    acc[1][1] = __builtin_amdgcn_mfma_f32_16x16x32_bf16(a1h, b1h, acc[1][1], 0, 0, 0);
    acc[2][0] = __builtin_amdgcn_mfma_f32_16x16x32_bf16(a2h, b0h, acc[2][0], 0, 0, 0);
    acc[2][1] = __builtin_amdgcn_mfma_f32_16x16x32_bf16(a2h, b1h, acc[2][1], 0, 0, 0);
    acc[0][0] = __builtin_amdgcn_mfma_f32_16x16x32_bf16(a0h, b0l, acc[0][0], 0, 0, 0);
    acc[0][1] = __builtin_amdgcn_mfma_f32_16x16x32_bf16(a0h, b1l, acc[0][1], 0, 0, 0);
    acc[1][0] = __builtin_amdgcn_mfma_f32_16x16x32_bf16(a1h, b0l, acc[1][0], 0, 0, 0);
    acc[1][1] = __builtin_amdgcn_mfma_f32_16x16x32_bf16(a1h, b1l, acc[1][1], 0, 0, 0);
    acc[2][0] = __builtin_amdgcn_mfma_f32_16x16x32_bf16(a2h, b0l, acc[2][0], 0, 0, 0);
    acc[2][1] = __builtin_amdgcn_mfma_f32_16x16x32_bf16(a2h, b1l, acc[2][1], 0, 0, 0);
    acc[0][0] = __builtin_amdgcn_mfma_f32_16x16x32_bf16(a0l, b0h, acc[0][0], 0, 0, 0);
    acc[0][1] = __builtin_amdgcn_mfma_f32_16x16x32_bf16(a0l, b1h, acc[0][1], 0, 0, 0);
    acc[1][0] = __builtin_amdgcn_mfma_f32_16x16x32_bf16(a1l, b0h, acc[1][0], 0, 0, 0);
    acc[1][1] = __builtin_amdgcn_mfma_f32_16x16x32_bf16(a1l, b1h, acc[1][1], 0, 0, 0);
    acc[2][0] = __builtin_amdgcn_mfma_f32_16x16x32_bf16(a2l, b0h, acc[2][0], 0, 0, 0);
    acc[2][1] = __builtin_amdgcn_mfma_f32_16x16x32_bf16(a2l, b1h, acc[2][1], 0, 0, 0);
  }
  __syncthreads();  // all waves done reading Ahi/Alo before zn/uu overwrite them

  // Epilogue: bias + relu -> RAW zn (fp32) over the staging region.
#pragma unroll
  for (int jn = 0; jn < 2; ++jn) {
    const int nt = jn ? nt1 : nt0;
    const int col = nt * 16 + ml;
    const float bias = jn ? bias1 : bias0;
#pragma unroll
    for (int mt = 0; mt < 3; ++mt) {
#pragma unroll
      for (int r = 0; r < 4; ++r) {
        const int row = mt * 16 + q * 4 + r;
        float v = fmaxf(acc[mt][jn][r] + bias, 0.f);
        if (row < 33) zn[row * ZS + col] = v;
      }
    }
  }
  __syncthreads();

  // Norms per (row,k); seed pp for iter 0 (uniform p=1/8, nrm folded).
  // Lane remap: row fast-varying so consecutive lanes read distinct rows
  // (distinct bank groups) — kills the 4-way b128 conflicts of k-fast order.
  {
    const int rowr = (tid & 7) | ((tid >> 6) << 3);  // 0..31
    const int kr = (tid >> 3) & 7;                   // 0..7
    const float4v* zp = (const float4v*)&zn[rowr * ZS + kr * 16];
    float4v a = zp[0], b = zp[1], c = zp[2], d = zp[3];
    float ss = a[0]*a[0]+a[1]*a[1]+a[2]*a[2]+a[3]*a[3]
             + b[0]*b[0]+b[1]*b[1]+b[2]*b[2]+b[3]*b[3]
             + c[0]*c[0]+c[1]*c[1]+c[2]*c[2]+c[3]*c[3]
             + d[0]*d[0]+d[1]*d[1]+d[2]*d[2]+d[3]*d[3];
    float nv = 1.f / fmaxf(sqrtf(ss), 1e-12f);
    nrm[rowr * 8 + kr] = nv;
    pp[kr * PPS + rowr] = nv * 0.125f;
  }
  if (tid < 8) {  // self row 32, k = tid
    const float4v* zp = (const float4v*)&zn[32 * ZS + tid * 16];
    float4v a = zp[0], b = zp[1], c = zp[2], d = zp[3];
    float ss = a[0]*a[0]+a[1]*a[1]+a[2]*a[2]+a[3]*a[3]
             + b[0]*b[0]+b[1]*b[1]+b[2]*b[2]+b[3]*b[3]
             + c[0]*c[0]+c[1]*c[1]+c[2]*c[2]+c[3]*c[3]
             + d[0]*d[0]+d[1]*d[1]+d[2]*d[2]+d[3]*d[3];
    float nv = 1.f / fmaxf(sqrtf(ss), 1e-12f);
    nrm[256 + tid] = nv;
  }
  __syncthreads();

  // ---------------- Routing: 3 iterations ----------------
  const int k2 = tid >> 5, half = (tid >> 4) & 1, c2 = tid & 15;
  // Loop-invariant self-capsule terms (zn row 32 / nrm[256+] never rewritten).
  const float selfw = nrm[256 + k2];
  const float selfz = zn[32 * ZS + k2 * 16 + c2];
  // pass1 lane remap (row fast, k slow): softmax reduce via xor 8,16,32.
  const int k1 = (lane >> 3) & 7;
  const int n1 = (lane & 7) | (wv << 3);
  for (int it = 0; it < 3; ++it) {
    if (it > 0) {
      // pass1: logits per (n,k); softmax over k; pp[k][n] = prob * nrm[n,k].
      const float4v* up = (const float4v*)&uu[k1 * 16];
      float4v u0 = up[0], u1 = up[1], u2 = up[2], u3 = up[3];
      const float4v* zp = (const float4v*)&zn[n1 * ZS + k1 * 16];
      float4v z0 = zp[0], z1 = zp[1], z2 = zp[2], z3 = zp[3];
      float dot = u0[0]*z0[0]+u0[1]*z0[1]+u0[2]*z0[2]+u0[3]*z0[3]
                + u1[0]*z1[0]+u1[1]*z1[1]+u1[2]*z1[2]+u1[3]*z1[3]
                + u2[0]*z2[0]+u2[1]*z2[1]+u2[2]*z2[2]+u2[3]*z2[3]
                + u3[0]*z3[0]+u3[1]*z3[1]+u3[2]*z3[2]+u3[3]*z3[3];
      const float nv = nrm[n1 * 8 + k1];
      float logit = dot * nv;  // TAU = 1
      float m = logit;
      m = fmaxf(m, __shfl_xor(m, 8));
      m = fmaxf(m, __shfl_xor(m, 16));
      m = fmaxf(m, __shfl_xor(m, 32));
      float e = __expf(logit - m);
      float s = e;
      s += __shfl_xor(s, 8);
      s += __shfl_xor(s, 16);
      s += __shfl_xor(s, 32);
      pp[k1 * PPS + n1] = (e / s) * nv;
      __syncthreads();
    }
    // pass2: 256 threads; (k2,c2) duplicated over half; each half sums 16 n's.
    // p-weights for this half: 16 consecutive floats, read as 4 broadcast float4.
    const float4v* pb = (const float4v*)&pp[k2 * PPS + half * 16];
    float4v p0 = pb[0], p1 = pb[1], p2 = pb[2], p3 = pb[3];
    float s = 0.f;
#pragma unroll
    for (int n0 = 0; n0 < 4; ++n0)
      s += p0[n0] * zn[(half * 16 + n0) * ZS + k2 * 16 + c2];
#pragma unroll
    for (int n0 = 0; n0 < 4; ++n0)
      s += p1[n0] * zn[(half * 16 + 4 + n0) * ZS + k2 * 16 + c2];
#pragma unroll
    for (int n0 = 0; n0 < 4; ++n0)
      s += p2[n0] * zn[(half * 16 + 8 + n0) * ZS + k2 * 16 + c2];
#pragma unroll
    for (int n0 = 0; n0 < 4; ++n0)
      s += p3[n0] * zn[(half * 16 + 12 + n0) * ZS + k2 * 16 + c2];
    s += __shfl_xor(s, 16);     // combine halves
    s += selfw * selfz;         // self capsule
    if (it < 2) {
      float ss = s * s;
      ss += __shfl_xor(ss, 1);
      ss += __shfl_xor(ss, 2);
      ss += __shfl_xor(ss, 4);
      ss += __shfl_xor(ss, 8);
      s *= 1.f / fmaxf(sqrtf(ss), 1e-12f);
      if (half == 0) uu[k2 * 16 + c2] = s;
      __syncthreads();
    } else if (half == 0) {
      float r = (s < 0.f) ? 0.f : s;
      const size_t oidx = bs * DD + k2 * 16 + c2;
      if (isf32) {
        ((float*)out)[oidx] = r;
      } else {
        unsigned int xb = __float_as_uint(r);
        unsigned int l = (xb >> 16) & 1u;
        ((unsigned short*)out)[oidx] = (unsigned short)((xb + 0x7fffu + l) >> 16);
      }
    }
  }
}

extern "C" void kernel_launch(void* const* d_in, const int* in_sizes, int n_in,
                              void* d_out, int out_size, void* d_ws, size_t ws_size,
                              hipStream_t stream) {
  (void)in_sizes; (void)n_in; (void)out_size; (void)ws_size;
  const void* selfv = d_in[0];
  const void* neighv = d_in[1];
  const void* w1 = d_in[2];
  const void* b1 = d_in[3];
  int* flag = (int*)d_ws;
  unsigned short* whi = (unsigned short*)((char*)d_ws + 64);
  unsigned short* wlo = (unsigned short*)((char*)d_ws + 64 + 32768);

  swizzle_w_kernel<<<64, 256, 0, stream>>>(w1, flag, whi, wlo);
  routing_kernel<<<8192, 256, 0, stream>>>(selfv, neighv, whi, wlo, b1, d_out, flag);
}